// Round 4
// baseline (622.510 us; speedup 1.0000x reference)
//
#include <hip/hip_runtime.h>

#define N_NODESC 50000
#define N_EDGESC 400000
#define N_GRAPHSC 128
#define IN_DIMC 768
#define HIDC 128
#define NCLSC 11
#define BN_EPSC 1e-5f
#define NB_AGG 8
#define NREP 64
#define SCAN_NB ((N_NODESC + 255) / 256)

typedef __bf16 bf16_t;
typedef __bf16 bf16x2 __attribute__((ext_vector_type(2)));
typedef __bf16 bf16x8 __attribute__((ext_vector_type(8)));
typedef float f32x4 __attribute__((ext_vector_type(4)));

typedef __attribute__((address_space(1))) void glb_void;
typedef __attribute__((address_space(3))) void lds_void;

__device__ __forceinline__ void cp16(const void* g, void* l) {
    // async global->LDS, 16B/lane; LDS dst = wave-uniform base + lane*16
    __builtin_amdgcn_global_load_lds((glb_void*)g, (lds_void*)l, 16, 0, 0);
}

__device__ __forceinline__ f32x4 mfma_16x16x32_bf16(bf16x8 a, bf16x8 b, f32x4 c) {
    return __builtin_amdgcn_mfma_f32_16x16x32_bf16(a, b, c, 0, 0, 0);
}

// [Cl|Cr] = BN?(A)[M,K] @ Wb^T, Wb [256,K] bf16. Tile 128x128xBK32.
// 1-D grid with XCD pair-colocation: (p,half=0)/(p,half=1) ids congruent mod 8
// -> same XCD L2 (R1 evidence: FETCH 152->78 MB. KEPT).
// R0-R3 evidence: time pinned to BYTES THROUGH THE cp16 (global_load_lds) QUEUE
// (~7.8 B/cy/CU), invariant to HBM traffic (R2) and lookahead depth (R3) ->
// per-CU DMA in-flight cap / HBM-miss latency is the binder.
// R4 change (MODE 0): A taken OFF the DMA queue entirely -- per-lane regular
// global_load_dwordx4 straight into registers (deep per-wave pipelining, no
// cap), fp32->bf16 cvt in regs, MFMA directly; A never touches LDS, so A has
// NO barrier coupling (unlike R1's failed reg->LDS staging). B stays on the
// proven cp16 depth-2 triple buffer (8 KB/block-iter, L2-hot).
// vmem stream per wave per iter = 2 cp16(B) + 8 loads(A) = 10 ops ->
// steady "B(it) landed" wait = vmcnt(20), tails 18/0.
// MODE 1: A bf16 via cp16 depth-2 triple buffer; BN scale/shift in-kernel,
// BN+ReLU post-LDS-read (proven, unchanged).
template<int MODE, int KC>
__global__ __launch_bounds__(256) void gemm_kernel(const void* __restrict__ Av,
                                                   const bf16_t* __restrict__ Wb,
                                                   const float* __restrict__ stats,
                                                   const float* __restrict__ g,
                                                   const float* __restrict__ be,
                                                   bf16_t* __restrict__ Cl,
                                                   bf16_t* __restrict__ Cr,
                                                   int M)
{
    constexpr int NK   = KC / 32;
    constexpr int ASZ  = 8192;                         // one A buffer (MODE 1 only)
    constexpr int BSZ  = 8192;                         // one B buffer
    constexpr int SCSZ = (MODE == 1) ? 1024 : 16;
    constexpr int SMSZ = ((MODE == 0) ? 3 * BSZ : 3 * ASZ + 3 * BSZ) + SCSZ;
    __shared__ __align__(16) unsigned char smem[SMSZ];
    unsigned char* Asm = smem;                                   // MODE 1 only
    unsigned char* Bsm = (MODE == 0) ? smem : smem + 3 * ASZ;
    float* scS = (float*)(smem + SMSZ - SCSZ);

    // ---- XCD pair-colocation decode (1-D grid of ((nP+7)/8)*16 blocks) ----
    const int bid  = blockIdx.x;
    const int p    = ((bid >> 4) << 3) + (bid & 7);
    const int half = (bid >> 3) & 1;
    if (p * 128 >= M) return;                          // uniform early-out (pad blocks)
    const int m0 = p * 128;

    const int t    = threadIdx.x;
    const int wid  = t >> 6;
    const int lane = t & 63;
    const int wm   = (wid >> 1) * 64;
    const int wn   = (wid & 1) * 64;
    const int l16  = lane & 15;
    const int quad = lane >> 4;

    // ---- B async-loader sources (XOR swizzle folded into the global side) ----
    const char* bSrc[2]; int bDst[2];
#pragma unroll
    for (int s = 0; s < 2; s++) {
        int L = (s * 4 + wid) * 64 + lane;   // 16B-chunk slot; LDS byte = L*16
        int r = L >> 2;
        int c = (L & 3) ^ ((r >> 1) & 3);
        bSrc[s] = (const char*)(Wb + (size_t)(half * 128 + r) * KC + c * 8);
        bDst[s] = (s * 4 + wid) * 1024;
    }

    // ---- MODE 1: A async-loader sources ----
    const char* aSrc[2]; int aDst[2];
    if constexpr (MODE == 1) {
#pragma unroll
        for (int s = 0; s < 2; s++) {
            int L = (s * 4 + wid) * 64 + lane;
            int r = L >> 2;
            int c = (L & 3) ^ ((r >> 1) & 3);
            int row = m0 + r; if (row > M - 1) row = M - 1;   // clamp; never stored
            aSrc[s] = (const char*)Av + ((size_t)row * KC + (size_t)c * 8) * 2;
            aDst[s] = (s * 4 + wid) * 1024;
        }
    }

    // ---- MODE 0: per-lane direct A fragment pointers (global -> regs) ----
    // fragment i: row = m0 + wm + i*16 + l16, k-window = quad*8 (8 fp32 = 32B)
    const float* aG[4];
    if constexpr (MODE == 0) {
#pragma unroll
        for (int i = 0; i < 4; i++) {
            int r = m0 + wm + i * 16 + l16; if (r > M - 1) r = M - 1;  // clamp; never stored
            aG[i] = (const float*)Av + (size_t)r * KC + quad * 8;
        }
    }

    // ---- fragment LDS byte offsets within one buffer ----
    int aOff[4], bOff[4];
#pragma unroll
    for (int i = 0; i < 4; i++) {
        int ra = wm + i * 16 + l16;
        aOff[i] = ra * 64 + ((quad ^ ((ra >> 1) & 3)) * 16);   // MODE 1 only
        int rb = wn + i * 16 + l16;
        bOff[i] = rb * 64 + ((quad ^ ((rb >> 1) & 3)) * 16);
    }

    if (MODE == 1) {
        // fused BN finalize: reduce the NREP stat replicas -> scale/shift in LDS.
        if (t < HIDC) {
            float sum = 0.f, sumsq = 0.f;
            for (int r = 0; r < NREP; r++) {
                sum   += stats[r * 256 + t];
                sumsq += stats[r * 256 + HIDC + t];
            }
            float invM = 1.0f / (float)M;
            float mean = sum * invM;
            float var  = sumsq * invM - mean * mean;
            float s = rsqrtf(var + BN_EPSC) * g[t];
            scS[t] = s;
            scS[HIDC + t] = be[t] - mean * s;
        }
        __syncthreads();
    }

    f32x4 acc[4][4] = {};

    if constexpr (MODE == 0) {
        float4 aEv[4][2], aOd[4][2];    // A(it) / A(it+1) register double buffer

        // ---- prologue: B(0),B(1) via cp16; A(0) -> regs ----
#pragma unroll
        for (int s = 0; s < 2; s++) cp16(bSrc[s], Bsm + bDst[s]);
#pragma unroll
        for (int i = 0; i < 4; i++) {
            aEv[i][0] = *(const float4*)(aG[i]);
            aEv[i][1] = *(const float4*)(aG[i] + 4);
        }
#pragma unroll
        for (int s = 0; s < 2; s++) cp16(bSrc[s] + 64, Bsm + BSZ + bDst[s]);

        for (int it = 0; it < NK; ++it) {
            // issue B(it+2) into buffer (it+2)%3 (read-safe: freed at prev barrier)
            if (it + 2 < NK) {
                const size_t kb = (size_t)(it + 2) * 64;
                const int nb = (it + 2) % 3;
#pragma unroll
                for (int s = 0; s < 2; s++) cp16(bSrc[s] + kb, Bsm + nb * BSZ + bDst[s]);
            }
            // issue A(it+1) into the other reg set (starts while we wait on B)
            if (it + 1 < NK) {
                const size_t ka = (size_t)(it + 1) * 32;
                if ((it & 1) == 0) {
#pragma unroll
                    for (int i = 0; i < 4; i++) {
                        aOd[i][0] = *(const float4*)(aG[i] + ka);
                        aOd[i][1] = *(const float4*)(aG[i] + ka + 4);
                    }
                } else {
#pragma unroll
                    for (int i = 0; i < 4; i++) {
                        aEv[i][0] = *(const float4*)(aG[i] + ka);
                        aEv[i][1] = *(const float4*)(aG[i] + ka + 4);
                    }
                }
            }
            // B(it) landed: everything younger = up to 2 iters x 10 vmem ops
            if (it + 2 < NK)      asm volatile("s_waitcnt vmcnt(20)" ::: "memory");
            else if (it + 1 < NK) asm volatile("s_waitcnt vmcnt(18)" ::: "memory");
            else                  asm volatile("s_waitcnt vmcnt(0)"  ::: "memory");
            asm volatile("s_barrier" ::: "memory");

            // cvt A(it) fp32 regs -> bf16 fragments (compiler inserts the reg waits)
            bf16x8 af[4], bfr[4];
            if ((it & 1) == 0) {
#pragma unroll
                for (int i = 0; i < 4; i++) {
                    af[i][0] = (bf16_t)aEv[i][0].x; af[i][1] = (bf16_t)aEv[i][0].y;
                    af[i][2] = (bf16_t)aEv[i][0].z; af[i][3] = (bf16_t)aEv[i][0].w;
                    af[i][4] = (bf16_t)aEv[i][1].x; af[i][5] = (bf16_t)aEv[i][1].y;
                    af[i][6] = (bf16_t)aEv[i][1].z; af[i][7] = (bf16_t)aEv[i][1].w;
                }
            } else {
#pragma unroll
                for (int i = 0; i < 4; i++) {
                    af[i][0] = (bf16_t)aOd[i][0].x; af[i][1] = (bf16_t)aOd[i][0].y;
                    af[i][2] = (bf16_t)aOd[i][0].z; af[i][3] = (bf16_t)aOd[i][0].w;
                    af[i][4] = (bf16_t)aOd[i][1].x; af[i][5] = (bf16_t)aOd[i][1].y;
                    af[i][6] = (bf16_t)aOd[i][1].z; af[i][7] = (bf16_t)aOd[i][1].w;
                }
            }
            const unsigned char* Bb = Bsm + (it % 3) * BSZ;
#pragma unroll
            for (int j = 0; j < 4; j++)
                bfr[j] = *(const bf16x8*)(Bb + bOff[j]);
#pragma unroll
            for (int i = 0; i < 4; i++)
#pragma unroll
                for (int j = 0; j < 4; j++)
                    acc[i][j] = mfma_16x16x32_bf16(af[i], bfr[j], acc[i][j]);

            asm volatile("s_barrier" ::: "memory");   // frees buffer (it)%3 for it+3... (cp16 order)
        }
    } else {
        // ---- depth-2 triple buffer (proven structure, unchanged) ----
#pragma unroll
        for (int s = 0; s < 2; s++) cp16(aSrc[s], Asm + aDst[s]);
#pragma unroll
        for (int s = 0; s < 2; s++) cp16(bSrc[s], Bsm + bDst[s]);
#pragma unroll
        for (int s = 0; s < 2; s++) cp16(aSrc[s] + 64, Asm + ASZ + aDst[s]);
#pragma unroll
        for (int s = 0; s < 2; s++) cp16(bSrc[s] + 64, Bsm + BSZ + bDst[s]);

        for (int it = 0; it < NK; ++it) {
            if (it + 2 < NK) {
                const size_t kb2 = (size_t)(it + 2) * 64;
                const int nb = (it + 2) % 3;
#pragma unroll
                for (int s = 0; s < 2; s++) cp16(aSrc[s] + kb2, Asm + nb * ASZ + aDst[s]);
#pragma unroll
                for (int s = 0; s < 2; s++) cp16(bSrc[s] + kb2, Bsm + nb * BSZ + bDst[s]);
                asm volatile("s_waitcnt vmcnt(8)" ::: "memory");
            } else if (it + 1 < NK) {
                asm volatile("s_waitcnt vmcnt(4)" ::: "memory");
            } else {
                asm volatile("s_waitcnt vmcnt(0)" ::: "memory");
            }
            asm volatile("s_barrier" ::: "memory");

            const unsigned char* Ab = Asm + (it % 3) * ASZ;
            const unsigned char* Bb = Bsm + (it % 3) * BSZ;
            bf16x8 af[4], bfr[4];
            float4 s0 = *(const float4*)&scS[it * 32 + quad * 8];
            float4 s1 = *(const float4*)&scS[it * 32 + quad * 8 + 4];
            float4 h0 = *(const float4*)&scS[HIDC + it * 32 + quad * 8];
            float4 h1 = *(const float4*)&scS[HIDC + it * 32 + quad * 8 + 4];
            float ss[8] = {s0.x, s0.y, s0.z, s0.w, s1.x, s1.y, s1.z, s1.w};
            float hh[8] = {h0.x, h0.y, h0.z, h0.w, h1.x, h1.y, h1.z, h1.w};
#pragma unroll
            for (int i = 0; i < 4; i++) {
                bf16x8 raw = *(const bf16x8*)(Ab + aOff[i]);
#pragma unroll
                for (int e = 0; e < 8; e++)
                    af[i][e] = (bf16_t)fmaxf(fmaf((float)raw[e], ss[e], hh[e]), 0.0f);
            }
#pragma unroll
            for (int j = 0; j < 4; j++)
                bfr[j] = *(const bf16x8*)(Bb + bOff[j]);
#pragma unroll
            for (int i = 0; i < 4; i++)
#pragma unroll
                for (int j = 0; j < 4; j++)
                    acc[i][j] = mfma_16x16x32_bf16(af[i], bfr[j], acc[i][j]);

            asm volatile("s_barrier" ::: "memory");
        }
    }

    // C/D layout (m89-verified, validated rounds 1-9)
    bf16_t* C = half ? Cr : Cl;
#pragma unroll
    for (int i = 0; i < 4; i++) {
        int rowb = m0 + wm + i * 16 + quad * 4;
#pragma unroll
        for (int j = 0; j < 4; j++) {
            int colh = wn + j * 16 + l16;
#pragma unroll
            for (int rr = 0; rr < 4; rr++) {
                int row = rowb + rr;
                if (row < M) C[(size_t)row * HIDC + colh] = (bf16_t)acc[i][j][rr];
            }
        }
    }
}

// ---------- fused init: weight converts + zero degi/stats ----------
__global__ void init_kernel(const float* __restrict__ W1l, const float* __restrict__ W1r,
                            const float* __restrict__ W2l, const float* __restrict__ W2r,
                            const float* __restrict__ W3l, const float* __restrict__ W3r,
                            bf16_t* __restrict__ Wb1, bf16_t* __restrict__ Wb2,
                            bf16_t* __restrict__ Wb3,
                            int* __restrict__ degi, float* __restrict__ stats)
{
    const int NW1 = 128 * IN_DIMC;
    const int NW2 = 128 * HIDC;
    const int NS  = 3 * NREP * 256;
    int j = blockIdx.x * blockDim.x + threadIdx.x;
    if (j < 2 * NW1) { Wb1[j] = (bf16_t)((j < NW1) ? W1l[j] : W1r[j - NW1]); return; }
    j -= 2 * NW1;
    if (j < 2 * NW2) { Wb2[j] = (bf16_t)((j < NW2) ? W2l[j] : W2r[j - NW2]); return; }
    j -= 2 * NW2;
    if (j < 2 * NW2) { Wb3[j] = (bf16_t)((j < NW2) ? W3l[j] : W3r[j - NW2]); return; }
    j -= 2 * NW2;
    if (j < NS) { stats[j] = 0.0f; return; }
    j -= NS;
    if (j < N_NODESC) degi[j] = 0;
}

// ---------- CSR build ----------
__global__ void degi_kernel(const int* __restrict__ ei, int* __restrict__ degi) {
    int e = blockIdx.x * blockDim.x + threadIdx.x;
    if (e < N_EDGESC) atomicAdd(&degi[ei[N_EDGESC + e]], 1);
}

__global__ __launch_bounds__(256) void scan1_kernel(const int* __restrict__ degi,
                                                    int* __restrict__ local,
                                                    int* __restrict__ partials)
{
    __shared__ int tmp[256];
    const int t = threadIdx.x;
    const int i = blockIdx.x * 256 + t;
    int v = (i < N_NODESC) ? degi[i] : 0;
    tmp[t] = v;
    __syncthreads();
    for (int off = 1; off < 256; off <<= 1) {
        int u = (t >= off) ? tmp[t - off] : 0;
        __syncthreads();
        tmp[t] += u;
        __syncthreads();
    }
    if (i < N_NODESC) local[i] = tmp[t] - v;
    if (t == 255) partials[blockIdx.x] = tmp[255];
}

// scan3 with the 196-partial scan folded in (replaces the scan2 dispatch)
__global__ __launch_bounds__(256) void scan3_kernel(const int* __restrict__ local,
                                                    const int* __restrict__ partials,
                                                    int* __restrict__ rowptr,
                                                    int* __restrict__ cursor)
{
    __shared__ int inc[256];
    __shared__ int orig[256];
    const int t = threadIdx.x;
    int v = (t < SCAN_NB) ? partials[t] : 0;
    inc[t] = v; orig[t] = v;
    __syncthreads();
    for (int off = 1; off < 256; off <<= 1) {
        int u = (t >= off) ? inc[t - off] : 0;
        __syncthreads();
        inc[t] += u;
        __syncthreads();
    }
    const int boff = inc[blockIdx.x] - orig[blockIdx.x];   // exclusive offset, broadcast
    const int i = blockIdx.x * 256 + t;
    if (i < N_NODESC) {
        int r = local[i] + boff;
        rowptr[i] = r;
        cursor[i] = r;
    }
    if (i == 0) rowptr[N_NODESC] = N_EDGESC;
}

__global__ void fill_kernel(const int* __restrict__ ei, int* __restrict__ cursor,
                            int* __restrict__ col) {
    int e = blockIdx.x * blockDim.x + threadIdx.x;
    if (e >= N_EDGESC) return;
    int d = ei[N_EDGESC + e];
    int pos = atomicAdd(&cursor[d], 1);
    col[pos] = ei[e];
}

// ---------- fused CSR-gather mean-agg + bias + Pr + BN partial sums ----------
// NO device-scope fences (R8 lesson: per-block fences on 8-XCD CDNA cost ~250us/layer).
__global__ __launch_bounds__(128) void agg_combine_kernel(const int* __restrict__ rowptr,
                                                          const int* __restrict__ col,
                                                          const bf16_t* __restrict__ Plb,
                                                          const bf16_t* __restrict__ Prb,
                                                          const float* __restrict__ bias,
                                                          bf16_t* __restrict__ Hb,
                                                          float* __restrict__ stats, int M)
{
    const int lane = threadIdx.x & 63;
    const int wv   = threadIdx.x >> 6;
    const int c0   = lane * 2;
    const float b0 = bias[c0], b1v = bias[c0 + 1];
    float s0 = 0.f, s1 = 0.f, q0 = 0.f, q1 = 0.f;
    const int n0 = blockIdx.x * NB_AGG + wv * (NB_AGG / 2);
    for (int rr = 0; rr < NB_AGG / 2; rr++) {
        int n = n0 + rr;
        if (n >= M) break;
        int lo = rowptr[n], hi = rowptr[n + 1];
        float a0 = 0.f, a1 = 0.f;
        for (int e = lo; e < hi; e += 8) {
            int rem = hi - e;
            int idx[8];
#pragma unroll
            for (int j = 0; j < 8; j++) {
                int ee = e + j; if (ee > hi - 1) ee = hi - 1;
                idx[j] = col[ee];                 // broadcast loads
            }
            bf16x2 v[8];
#pragma unroll
            for (int j = 0; j < 8; j++)
                v[j] = *(const bf16x2*)&Plb[(size_t)idx[j] * HIDC + c0];  // 8 in flight
#pragma unroll
            for (int j = 0; j < 8; j++)
                if (j < rem) { a0 += (float)v[j][0]; a1 += (float)v[j][1]; }
        }
        int d = hi - lo;
        float inv = 1.0f / (float)(d > 0 ? d : 1);
        bf16x2 pr = *(const bf16x2*)&Prb[(size_t)n * HIDC + c0];
        float pre0 = fmaf(a0, inv, b0) + (float)pr[0];
        float pre1 = fmaf(a1, inv, b1v) + (float)pr[1];
        bf16x2 hv; hv[0] = (bf16_t)pre0; hv[1] = (bf16_t)pre1;
        *(bf16x2*)&Hb[(size_t)n * HIDC + c0] = hv;
        s0 += pre0; s1 += pre1; q0 += pre0 * pre0; q1 += pre1 * pre1;
    }
    const int rep = (blockIdx.x * 2 + wv) & (NREP - 1);
    atomicAdd(&stats[rep * 256 + c0], s0);
    atomicAdd(&stats[rep * 256 + c0 + 1], s1);
    atomicAdd(&stats[rep * 256 + HIDC + c0], q0);
    atomicAdd(&stats[rep * 256 + HIDC + c0 + 1], q1);
}

// ---------- fused BN3-finalize + pool + linear head ----------
__global__ __launch_bounds__(128) void poolhead_kernel(const bf16_t* __restrict__ Hb,
                                                       const float* __restrict__ stats,
                                                       const float* __restrict__ g,
                                                       const float* __restrict__ be,
                                                       const int* __restrict__ batch,
                                                       const float* __restrict__ Wlin,
                                                       const float* __restrict__ blin,
                                                       float* __restrict__ out, int M)
{
    __shared__ float sp[HIDC];
    int gph = blockIdx.x;
    int c   = threadIdx.x;
    float sum = 0.f, sumsq = 0.f;
    for (int r = 0; r < NREP; r++) {
        sum   += stats[r * 256 + c];
        sumsq += stats[r * 256 + HIDC + c];
    }
    float invM = 1.0f / (float)M;
    float mean = sum * invM;
    float var  = sumsq * invM - mean * mean;
    float s = rsqrtf(var + BN_EPSC) * g[c];
    float h = be[c] - mean * s;

    int lo = 0, hi = M;
    while (lo < hi) { int m = (lo + hi) >> 1; if (batch[m] < gph) lo = m + 1; else hi = m; }
    int lo2 = lo, hi2 = M;
    while (lo2 < hi2) { int m = (lo2 + hi2) >> 1; if (batch[m] < gph + 1) lo2 = m + 1; else hi2 = m; }
    float mx = -INFINITY;
    for (int rr = lo; rr < lo2; rr++)
        mx = fmaxf(mx, fmaf((float)Hb[(size_t)rr * HIDC + c], s, h));
    sp[c] = mx;
    __syncthreads();
    if (c < NCLSC) {
        float acc = blin[c];
        for (int k = 0; k < HIDC; k++) acc += sp[k] * Wlin[c * HIDC + k];
        out[gph * NCLSC + c] = acc;
    }
}

extern "C" void kernel_launch(void* const* d_in, const int* in_sizes, int n_in,
                              void* d_out, int out_size, void* d_ws, size_t ws_size,
                              hipStream_t stream)
{
    const float* x     = (const float*)d_in[0];
    const int*   ei    = (const int*)d_in[1];
    const int*   batch = (const int*)d_in[2];
    const float* W1l = (const float*)d_in[3];
    const float* b1  = (const float*)d_in[4];
    const float* W1r = (const float*)d_in[5];
    const float* g1  = (const float*)d_in[6];
    const float* be1 = (const float*)d_in[7];
    const float* W2l = (const float*)d_in[8];
    const float* b2  = (const float*)d_in[9];
    const float* W2r = (const float*)d_in[10];
    const float* g2  = (const float*)d_in[11];
    const float* be2 = (const float*)d_in[12];
    const float* W3l = (const float*)d_in[13];
    const float* b3  = (const float*)d_in[14];
    const float* W3r = (const float*)d_in[15];
    const float* g3  = (const float*)d_in[16];
    const float* be3 = (const float*)d_in[17];
    const float* Wlin = (const float*)d_in[18];
    const float* blin = (const float*)d_in[19];

    const int M = N_NODESC;

    // workspace carve (16B aligned)
    char* w = (char*)d_ws;
    bf16_t* Plb  = (bf16_t*)w;  w += (size_t)M * HIDC * 2;
    bf16_t* Prb  = (bf16_t*)w;  w += (size_t)M * HIDC * 2;
    bf16_t* Hb   = (bf16_t*)w;  w += (size_t)M * HIDC * 2;
    bf16_t* Wb1  = (bf16_t*)w;  w += (size_t)256 * IN_DIMC * 2;
    bf16_t* Wb2  = (bf16_t*)w;  w += (size_t)256 * HIDC * 2;
    bf16_t* Wb3  = (bf16_t*)w;  w += (size_t)256 * HIDC * 2;
    int*   rowptr= (int*)w;     w += (size_t)(M + 16) * 4;
    int*   col   = (int*)w;     w += (size_t)N_EDGESC * 4;
    int*   cursor= (int*)w;     w += (size_t)M * 4;
    int*   degi  = (int*)w;     w += (size_t)M * 4;
    int*   slocal= (int*)w;     w += (size_t)M * 4;
    int*   spart = (int*)w;     w += 256 * 4;
    float* stats = (float*)w;   w += (size_t)3 * NREP * 256 * 4;   // zeroed in init

    float* stats1 = stats;
    float* stats2 = stats + NREP * 256;
    float* stats3 = stats + 2 * NREP * 256;

    // 1-D grid, XCD pair-colocation decode in-kernel: (p,0)/(p,1) ids differ by 8
    const int nP = (M + 127) / 128;
    const dim3 gemm_grid(((nP + 7) / 8) * 16);
    const int agg_blocks = (M + NB_AGG - 1) / NB_AGG;
    const int init_total = 2 * 128 * IN_DIMC + 4 * 128 * HIDC + 3 * NREP * 256 + M;

    // ---- init (weights + zeros, one dispatch) ----
    init_kernel<<<(init_total + 255) / 256, 256, 0, stream>>>(W1l, W1r, W2l, W2r, W3l, W3r,
                                                              Wb1, Wb2, Wb3, degi, stats);
    // ---- CSR build (4 dispatches) ----
    degi_kernel<<<(N_EDGESC + 255) / 256, 256, 0, stream>>>(ei, degi);
    scan1_kernel<<<SCAN_NB, 256, 0, stream>>>(degi, slocal, spart);
    scan3_kernel<<<SCAN_NB, 256, 0, stream>>>(slocal, spart, rowptr, cursor);
    fill_kernel<<<(N_EDGESC + 255) / 256, 256, 0, stream>>>(ei, cursor, col);

    // ---- layer 1 (K=768, A=x fp32 direct-to-regs, B cp16 depth-2) ----
    gemm_kernel<0, IN_DIMC><<<gemm_grid, 256, 0, stream>>>(x, Wb1, nullptr, nullptr, nullptr,
                                                           Plb, Prb, M);
    agg_combine_kernel<<<agg_blocks, 128, 0, stream>>>(rowptr, col, Plb, Prb, b1, Hb, stats1, M);

    // ---- layer 2 (K=128; BN1 finalize + BN1+ReLU fused into the GEMM) ----
    gemm_kernel<1, HIDC><<<gemm_grid, 256, 0, stream>>>(Hb, Wb2, stats1, g1, be1, Plb, Prb, M);
    agg_combine_kernel<<<agg_blocks, 128, 0, stream>>>(rowptr, col, Plb, Prb, b2, Hb, stats2, M);

    // ---- layer 3 (K=128; BN2 finalize + BN2+ReLU fused) ----
    gemm_kernel<1, HIDC><<<gemm_grid, 256, 0, stream>>>(Hb, Wb3, stats2, g2, be2, Plb, Prb, M);
    agg_combine_kernel<<<agg_blocks, 128, 0, stream>>>(rowptr, col, Plb, Prb, b3, Hb, stats3, M);

    // ---- BN3 finalize + pool + head (one dispatch) ----
    poolhead_kernel<<<N_GRAPHSC, 128, 0, stream>>>(Hb, stats3, g3, be3, batch, Wlin, blin,
                                                   (float*)d_out, M);
}

// Round 5
// 556.849 us; speedup vs baseline: 1.1179x; 1.1179x over previous
//
#include <hip/hip_runtime.h>

#define N_NODESC 50000
#define N_EDGESC 400000
#define N_GRAPHSC 128
#define IN_DIMC 768
#define HIDC 128
#define NCLSC 11
#define BN_EPSC 1e-5f
#define NB_AGG 8
#define NREP 64
#define SCAN_NB ((N_NODESC + 255) / 256)

typedef __bf16 bf16_t;
typedef __bf16 bf16x2 __attribute__((ext_vector_type(2)));
typedef __bf16 bf16x8 __attribute__((ext_vector_type(8)));
typedef float f32x4 __attribute__((ext_vector_type(4)));

typedef __attribute__((address_space(1))) void glb_void;
typedef __attribute__((address_space(3))) void lds_void;

__device__ __forceinline__ void cp16(const void* g, void* l) {
    // async global->LDS, 16B/lane; LDS dst = wave-uniform base + lane*16
    __builtin_amdgcn_global_load_lds((glb_void*)g, (lds_void*)l, 16, 0, 0);
}

__device__ __forceinline__ f32x4 mfma_16x16x32_bf16(bf16x8 a, bf16x8 b, f32x4 c) {
    return __builtin_amdgcn_mfma_f32_16x16x32_bf16(a, b, c, 0, 0, 0);
}

// ---------------- layer-1 GEMM: [Cl|Cr] = A[M,768]fp32 @ Wb^T, Wb[256,768]bf16
// R4 history: R0-R3 proved time is pinned to bytes pushed through the cp16
// queue (~7.6 B/cy/CU), invariant to HBM traffic (R2) and lookahead depth (R3);
// R4's per-lane A gather regressed (142us, request-rate bound).
// R5: ONE 128x256 tile per block (both W halves) -> A staged ONCE per panel:
// staged bytes 451->300 MB, blocks 784->391, 32 MFMA per barrier-pair per wave
// (2x compute per convoy). Depth-1 double buffer (R0-proven schedule), 64 KB
// LDS -> 2 blocks/CU (= measured residency of all prior variants).
__global__ __launch_bounds__(256, 2) void gemm_l1_kernel(const float* __restrict__ Av,
                                                         const bf16_t* __restrict__ Wb,
                                                         bf16_t* __restrict__ Cl,
                                                         bf16_t* __restrict__ Cr,
                                                         int M)
{
    constexpr int KC  = IN_DIMC;          // 768
    constexpr int NK  = KC / 32;          // 24
    constexpr int ASZ = 16384;            // fp32 128x32
    constexpr int BSZ = 16384;            // bf16 256x32
    __shared__ __align__(16) unsigned char smem[2 * ASZ + 2 * BSZ];
    unsigned char* Asm = smem;
    unsigned char* Bsm = smem + 2 * ASZ;

    const int m0   = blockIdx.x * 128;
    const int t    = threadIdx.x;
    const int wid  = t >> 6;
    const int lane = t & 63;
    const int wm   = (wid >> 1) * 64;     // row half
    const int l16  = lane & 15;
    const int quad = lane >> 4;

    // ---- A loader: 4 chunks/wave, 16 KB/iter, XOR swizzle on global side ----
    const char* aSrc[4]; int aDst[4];
#pragma unroll
    for (int s = 0; s < 4; s++) {
        int L = (s * 4 + wid) * 64 + lane;            // 16B slot; LDS byte = L*16
        int r = L >> 3;                               // 0..127
        int c = (L & 7) ^ (r & 7);                    // 8 chunks per 128B row
        int row = m0 + r; if (row > M - 1) row = M - 1;  // clamp; never stored
        aSrc[s] = (const char*)Av + ((size_t)row * KC + (size_t)c * 4) * 4;
        aDst[s] = (s * 4 + wid) * 1024;
    }
    // ---- B loader: 4 chunks/wave, 16 KB/iter (all 256 Wb rows) ----
    const char* bSrc[4]; int bDst[4];
#pragma unroll
    for (int s = 0; s < 4; s++) {
        int L = (s * 4 + wid) * 64 + lane;
        int r = L >> 2;                               // 0..255
        int c = (L & 3) ^ ((r >> 1) & 3);
        bSrc[s] = (const char*)(Wb + (size_t)r * KC + c * 8);
        bDst[s] = (s * 4 + wid) * 1024;
    }

    // ---- fragment LDS byte offsets ----
    int aOff[4][2], bOff[8];
#pragma unroll
    for (int i = 0; i < 4; i++) {
        int ra = wm + i * 16 + l16;
        aOff[i][0] = ra * 128 + (((2 * quad)     ^ (ra & 7)) * 16);
        aOff[i][1] = ra * 128 + (((2 * quad + 1) ^ (ra & 7)) * 16);
    }
    const int wnb = (wid & 1) * 128;                  // output-col half
#pragma unroll
    for (int j = 0; j < 8; j++) {
        int rb = wnb + j * 16 + l16;                  // 0..255
        bOff[j] = rb * 64 + ((quad ^ ((rb >> 1) & 3)) * 16);
    }

    f32x4 acc[4][8] = {};

    // ---- depth-1 double buffer (R0-proven schedule) ----
#pragma unroll
    for (int s = 0; s < 4; s++) cp16(aSrc[s], Asm + aDst[s]);
#pragma unroll
    for (int s = 0; s < 4; s++) cp16(bSrc[s], Bsm + bDst[s]);

    for (int it = 0; it < NK; ++it) {
        if (it + 1 < NK) {
            const size_t ka = (size_t)(it + 1) * 128;
            const size_t kb = (size_t)(it + 1) * 64;
            const int nb = (it + 1) & 1;
#pragma unroll
            for (int s = 0; s < 4; s++) cp16(aSrc[s] + ka, Asm + nb * ASZ + aDst[s]);
#pragma unroll
            for (int s = 0; s < 4; s++) cp16(bSrc[s] + kb, Bsm + nb * BSZ + bDst[s]);
            asm volatile("s_waitcnt vmcnt(8)" ::: "memory");   // drain iter-it only
        } else {
            asm volatile("s_waitcnt vmcnt(0)" ::: "memory");
        }
        asm volatile("s_barrier" ::: "memory");

        const unsigned char* Ab = Asm + (it & 1) * ASZ;
        const unsigned char* Bb = Bsm + (it & 1) * BSZ;
        bf16x8 af[4], bfr[8];
#pragma unroll
        for (int i = 0; i < 4; i++) {
            float4 u0 = *(const float4*)(Ab + aOff[i][0]);
            float4 u1 = *(const float4*)(Ab + aOff[i][1]);
            af[i][0] = (bf16_t)u0.x; af[i][1] = (bf16_t)u0.y;
            af[i][2] = (bf16_t)u0.z; af[i][3] = (bf16_t)u0.w;
            af[i][4] = (bf16_t)u1.x; af[i][5] = (bf16_t)u1.y;
            af[i][6] = (bf16_t)u1.z; af[i][7] = (bf16_t)u1.w;
        }
#pragma unroll
        for (int j = 0; j < 8; j++)
            bfr[j] = *(const bf16x8*)(Bb + bOff[j]);
#pragma unroll
        for (int i = 0; i < 4; i++)
#pragma unroll
            for (int j = 0; j < 8; j++)
                acc[i][j] = mfma_16x16x32_bf16(af[i], bfr[j], acc[i][j]);

        asm volatile("s_barrier" ::: "memory");   // protect buf reused next iter
    }

    // C/D layout (m89-verified); wave col-half -> Cl or Cr directly
    bf16_t* C = (wid & 1) ? Cr : Cl;
#pragma unroll
    for (int i = 0; i < 4; i++) {
        int rowb = m0 + wm + i * 16 + quad * 4;
#pragma unroll
        for (int j = 0; j < 8; j++) {
            int colh = j * 16 + l16;
#pragma unroll
            for (int rr = 0; rr < 4; rr++) {
                int row = rowb + rr;
                if (row < M) C[(size_t)row * HIDC + colh] = (bf16_t)acc[i][j][rr];
            }
        }
    }
}

// ---------------- hidden-layer GEMM (K=128): proven MODE-1 structure, unchanged
// A bf16 via cp16 depth-2 triple buffer; BN scale/shift computed in-kernel from
// stats replicas; BN+ReLU post-LDS-read. Pair-colocation grid (R1: FETCH halved).
__global__ __launch_bounds__(256) void gemm_hid_kernel(const bf16_t* __restrict__ Av,
                                                       const bf16_t* __restrict__ Wb,
                                                       const float* __restrict__ stats,
                                                       const float* __restrict__ g,
                                                       const float* __restrict__ be,
                                                       bf16_t* __restrict__ Cl,
                                                       bf16_t* __restrict__ Cr,
                                                       int M)
{
    constexpr int KC  = HIDC;             // 128
    constexpr int NK  = KC / 32;          // 4
    constexpr int ASZ = 8192;
    constexpr int BSZ = 8192;
    __shared__ __align__(16) unsigned char smem[3 * ASZ + 3 * BSZ + 1024];
    unsigned char* Asm = smem;
    unsigned char* Bsm = smem + 3 * ASZ;
    float* scS = (float*)(smem + 3 * ASZ + 3 * BSZ);

    const int bid  = blockIdx.x;
    const int p    = ((bid >> 4) << 3) + (bid & 7);
    const int half = (bid >> 3) & 1;
    if (p * 128 >= M) return;
    const int m0 = p * 128;

    const int t    = threadIdx.x;
    const int wid  = t >> 6;
    const int lane = t & 63;
    const int wm   = (wid >> 1) * 64;
    const int wn   = (wid & 1) * 64;
    const int l16  = lane & 15;
    const int quad = lane >> 4;

    const char* bSrc[2]; int bDst[2];
#pragma unroll
    for (int s = 0; s < 2; s++) {
        int L = (s * 4 + wid) * 64 + lane;
        int r = L >> 2;
        int c = (L & 3) ^ ((r >> 1) & 3);
        bSrc[s] = (const char*)(Wb + (size_t)(half * 128 + r) * KC + c * 8);
        bDst[s] = (s * 4 + wid) * 1024;
    }
    const char* aSrc[2]; int aDst[2];
#pragma unroll
    for (int s = 0; s < 2; s++) {
        int L = (s * 4 + wid) * 64 + lane;
        int r = L >> 2;
        int c = (L & 3) ^ ((r >> 1) & 3);
        int row = m0 + r; if (row > M - 1) row = M - 1;
        aSrc[s] = (const char*)Av + ((size_t)row * KC + (size_t)c * 8) * 2;
        aDst[s] = (s * 4 + wid) * 1024;
    }

    int aOff[4], bOff[4];
#pragma unroll
    for (int i = 0; i < 4; i++) {
        int ra = wm + i * 16 + l16;
        aOff[i] = ra * 64 + ((quad ^ ((ra >> 1) & 3)) * 16);
        int rb = wn + i * 16 + l16;
        bOff[i] = rb * 64 + ((quad ^ ((rb >> 1) & 3)) * 16);
    }

    // fused BN finalize -> scale/shift in LDS (drained before barrier)
    if (t < HIDC) {
        float sum = 0.f, sumsq = 0.f;
        for (int r = 0; r < NREP; r++) {
            sum   += stats[r * 256 + t];
            sumsq += stats[r * 256 + HIDC + t];
        }
        float invM = 1.0f / (float)M;
        float mean = sum * invM;
        float var  = sumsq * invM - mean * mean;
        float s = rsqrtf(var + BN_EPSC) * g[t];
        scS[t] = s;
        scS[HIDC + t] = be[t] - mean * s;
    }
    __syncthreads();

    f32x4 acc[4][4] = {};

#pragma unroll
    for (int s = 0; s < 2; s++) cp16(aSrc[s], Asm + aDst[s]);
#pragma unroll
    for (int s = 0; s < 2; s++) cp16(bSrc[s], Bsm + bDst[s]);
#pragma unroll
    for (int s = 0; s < 2; s++) cp16(aSrc[s] + 64, Asm + ASZ + aDst[s]);
#pragma unroll
    for (int s = 0; s < 2; s++) cp16(bSrc[s] + 64, Bsm + BSZ + bDst[s]);

    for (int it = 0; it < NK; ++it) {
        if (it + 2 < NK) {
            const size_t kb2 = (size_t)(it + 2) * 64;
            const int nb = (it + 2) % 3;
#pragma unroll
            for (int s = 0; s < 2; s++) cp16(aSrc[s] + kb2, Asm + nb * ASZ + aDst[s]);
#pragma unroll
            for (int s = 0; s < 2; s++) cp16(bSrc[s] + kb2, Bsm + nb * BSZ + bDst[s]);
            asm volatile("s_waitcnt vmcnt(8)" ::: "memory");
        } else if (it + 1 < NK) {
            asm volatile("s_waitcnt vmcnt(4)" ::: "memory");
        } else {
            asm volatile("s_waitcnt vmcnt(0)" ::: "memory");
        }
        asm volatile("s_barrier" ::: "memory");

        const unsigned char* Ab = Asm + (it % 3) * ASZ;
        const unsigned char* Bb = Bsm + (it % 3) * BSZ;
        bf16x8 af[4], bfr[4];
        float4 s0 = *(const float4*)&scS[it * 32 + quad * 8];
        float4 s1 = *(const float4*)&scS[it * 32 + quad * 8 + 4];
        float4 h0 = *(const float4*)&scS[HIDC + it * 32 + quad * 8];
        float4 h1 = *(const float4*)&scS[HIDC + it * 32 + quad * 8 + 4];
        float ss[8] = {s0.x, s0.y, s0.z, s0.w, s1.x, s1.y, s1.z, s1.w};
        float hh[8] = {h0.x, h0.y, h0.z, h0.w, h1.x, h1.y, h1.z, h1.w};
#pragma unroll
        for (int i = 0; i < 4; i++) {
            bf16x8 raw = *(const bf16x8*)(Ab + aOff[i]);
#pragma unroll
            for (int e = 0; e < 8; e++)
                af[i][e] = (bf16_t)fmaxf(fmaf((float)raw[e], ss[e], hh[e]), 0.0f);
        }
#pragma unroll
        for (int j = 0; j < 4; j++)
            bfr[j] = *(const bf16x8*)(Bb + bOff[j]);
#pragma unroll
        for (int i = 0; i < 4; i++)
#pragma unroll
            for (int j = 0; j < 4; j++)
                acc[i][j] = mfma_16x16x32_bf16(af[i], bfr[j], acc[i][j]);

        asm volatile("s_barrier" ::: "memory");
    }

    bf16_t* C = half ? Cr : Cl;
#pragma unroll
    for (int i = 0; i < 4; i++) {
        int rowb = m0 + wm + i * 16 + quad * 4;
#pragma unroll
        for (int j = 0; j < 4; j++) {
            int colh = wn + j * 16 + l16;
#pragma unroll
            for (int rr = 0; rr < 4; rr++) {
                int row = rowb + rr;
                if (row < M) C[(size_t)row * HIDC + colh] = (bf16_t)acc[i][j][rr];
            }
        }
    }
}

// ---------- fused init: weight converts + zero degi/stats ----------
__global__ void init_kernel(const float* __restrict__ W1l, const float* __restrict__ W1r,
                            const float* __restrict__ W2l, const float* __restrict__ W2r,
                            const float* __restrict__ W3l, const float* __restrict__ W3r,
                            bf16_t* __restrict__ Wb1, bf16_t* __restrict__ Wb2,
                            bf16_t* __restrict__ Wb3,
                            int* __restrict__ degi, float* __restrict__ stats)
{
    const int NW1 = 128 * IN_DIMC;
    const int NW2 = 128 * HIDC;
    const int NS  = 3 * NREP * 256;
    int j = blockIdx.x * blockDim.x + threadIdx.x;
    if (j < 2 * NW1) { Wb1[j] = (bf16_t)((j < NW1) ? W1l[j] : W1r[j - NW1]); return; }
    j -= 2 * NW1;
    if (j < 2 * NW2) { Wb2[j] = (bf16_t)((j < NW2) ? W2l[j] : W2r[j - NW2]); return; }
    j -= 2 * NW2;
    if (j < 2 * NW2) { Wb3[j] = (bf16_t)((j < NW2) ? W3l[j] : W3r[j - NW2]); return; }
    j -= 2 * NW2;
    if (j < NS) { stats[j] = 0.0f; return; }
    j -= NS;
    if (j < N_NODESC) degi[j] = 0;
}

// ---------- CSR build ----------
__global__ void degi_kernel(const int* __restrict__ ei, int* __restrict__ degi) {
    int e = blockIdx.x * blockDim.x + threadIdx.x;
    if (e < N_EDGESC) atomicAdd(&degi[ei[N_EDGESC + e]], 1);
}

__global__ __launch_bounds__(256) void scan1_kernel(const int* __restrict__ degi,
                                                    int* __restrict__ local,
                                                    int* __restrict__ partials)
{
    __shared__ int tmp[256];
    const int t = threadIdx.x;
    const int i = blockIdx.x * 256 + t;
    int v = (i < N_NODESC) ? degi[i] : 0;
    tmp[t] = v;
    __syncthreads();
    for (int off = 1; off < 256; off <<= 1) {
        int u = (t >= off) ? tmp[t - off] : 0;
        __syncthreads();
        tmp[t] += u;
        __syncthreads();
    }
    if (i < N_NODESC) local[i] = tmp[t] - v;
    if (t == 255) partials[blockIdx.x] = tmp[255];
}

// scan3 with the 196-partial scan folded in (replaces the scan2 dispatch)
__global__ __launch_bounds__(256) void scan3_kernel(const int* __restrict__ local,
                                                    const int* __restrict__ partials,
                                                    int* __restrict__ rowptr,
                                                    int* __restrict__ cursor)
{
    __shared__ int inc[256];
    __shared__ int orig[256];
    const int t = threadIdx.x;
    int v = (t < SCAN_NB) ? partials[t] : 0;
    inc[t] = v; orig[t] = v;
    __syncthreads();
    for (int off = 1; off < 256; off <<= 1) {
        int u = (t >= off) ? inc[t - off] : 0;
        __syncthreads();
        inc[t] += u;
        __syncthreads();
    }
    const int boff = inc[blockIdx.x] - orig[blockIdx.x];   // exclusive offset, broadcast
    const int i = blockIdx.x * 256 + t;
    if (i < N_NODESC) {
        int r = local[i] + boff;
        rowptr[i] = r;
        cursor[i] = r;
    }
    if (i == 0) rowptr[N_NODESC] = N_EDGESC;
}

__global__ void fill_kernel(const int* __restrict__ ei, int* __restrict__ cursor,
                            int* __restrict__ col) {
    int e = blockIdx.x * blockDim.x + threadIdx.x;
    if (e >= N_EDGESC) return;
    int d = ei[N_EDGESC + e];
    int pos = atomicAdd(&cursor[d], 1);
    col[pos] = ei[e];
}

// ---------- fused CSR-gather mean-agg + bias + Pr + BN partial sums ----------
// R5 restructure: round-based interleave -- the wave's 4 nodes issue their col
// loads together, then all (up to 32) row-gathers together, THEN accumulate.
// Cuts the per-wave dependent chain from ~8 serial latency hops (per-node
// loop) to ~2 per round. Uniform branches (lo/hi wave-uniform); no fences.
__global__ __launch_bounds__(128) void agg_combine_kernel(const int* __restrict__ rowptr,
                                                          const int* __restrict__ col,
                                                          const bf16_t* __restrict__ Plb,
                                                          const bf16_t* __restrict__ Prb,
                                                          const float* __restrict__ bias,
                                                          bf16_t* __restrict__ Hb,
                                                          float* __restrict__ stats, int M)
{
    const int lane = threadIdx.x & 63;
    const int wv   = threadIdx.x >> 6;
    const int c0   = lane * 2;
    const float b0 = bias[c0], b1v = bias[c0 + 1];
    const int n0 = blockIdx.x * NB_AGG + wv * (NB_AGG / 2);

    int lo[4], hi[4], pos[4];
    bf16x2 pr[4];
#pragma unroll
    for (int r = 0; r < 4; r++) {
        int n = n0 + r;
        lo[r] = (n < M) ? rowptr[n] : 0;
        hi[r] = (n < M) ? rowptr[n + 1] : 0;
        pos[r] = lo[r];
        if (n < M) pr[r] = *(const bf16x2*)&Prb[(size_t)n * HIDC + c0];
        else { pr[r][0] = (bf16_t)0.f; pr[r][1] = (bf16_t)0.f; }
    }

    float a0[4] = {0.f, 0.f, 0.f, 0.f}, a1[4] = {0.f, 0.f, 0.f, 0.f};

    for (;;) {
        int cnt[4];
        bool any = false;
#pragma unroll
        for (int r = 0; r < 4; r++) {
            int c = hi[r] - pos[r];
            cnt[r] = (c > 8) ? 8 : c;
            if (cnt[r] > 0) any = true;
        }
        if (!any) break;

        bf16x2 v[4][8];
#pragma unroll
        for (int r = 0; r < 4; r++) {
            if (cnt[r] > 0) {                       // wave-uniform branch
                int idx[8];
#pragma unroll
                for (int j = 0; j < 8; j++) {
                    int ee = pos[r] + j;
                    if (ee > hi[r] - 1) ee = hi[r] - 1;
                    idx[j] = col[ee];               // broadcast loads
                }
#pragma unroll
                for (int j = 0; j < 8; j++)
                    v[r][j] = *(const bf16x2*)&Plb[(size_t)idx[j] * HIDC + c0];
            }
        }
#pragma unroll
        for (int r = 0; r < 4; r++) {
            if (cnt[r] > 0) {
#pragma unroll
                for (int j = 0; j < 8; j++)
                    if (j < cnt[r]) { a0[r] += (float)v[r][j][0]; a1[r] += (float)v[r][j][1]; }
                pos[r] += cnt[r];
            }
        }
    }

    float s0 = 0.f, s1 = 0.f, q0 = 0.f, q1 = 0.f;
#pragma unroll
    for (int r = 0; r < 4; r++) {
        int n = n0 + r;
        if (n < M) {
            int d = hi[r] - lo[r];
            float inv = 1.0f / (float)(d > 0 ? d : 1);
            float pre0 = fmaf(a0[r], inv, b0) + (float)pr[r][0];
            float pre1 = fmaf(a1[r], inv, b1v) + (float)pr[r][1];
            bf16x2 hv; hv[0] = (bf16_t)pre0; hv[1] = (bf16_t)pre1;
            *(bf16x2*)&Hb[(size_t)n * HIDC + c0] = hv;
            s0 += pre0; s1 += pre1; q0 += pre0 * pre0; q1 += pre1 * pre1;
        }
    }
    const int rep = (blockIdx.x * 2 + wv) & (NREP - 1);
    atomicAdd(&stats[rep * 256 + c0], s0);
    atomicAdd(&stats[rep * 256 + c0 + 1], s1);
    atomicAdd(&stats[rep * 256 + HIDC + c0], q0);
    atomicAdd(&stats[rep * 256 + HIDC + c0 + 1], q1);
}

// ---------- fused BN3-finalize + pool + linear head ----------
__global__ __launch_bounds__(128) void poolhead_kernel(const bf16_t* __restrict__ Hb,
                                                       const float* __restrict__ stats,
                                                       const float* __restrict__ g,
                                                       const float* __restrict__ be,
                                                       const int* __restrict__ batch,
                                                       const float* __restrict__ Wlin,
                                                       const float* __restrict__ blin,
                                                       float* __restrict__ out, int M)
{
    __shared__ float sp[HIDC];
    int gph = blockIdx.x;
    int c   = threadIdx.x;
    float sum = 0.f, sumsq = 0.f;
    for (int r = 0; r < NREP; r++) {
        sum   += stats[r * 256 + c];
        sumsq += stats[r * 256 + HIDC + c];
    }
    float invM = 1.0f / (float)M;
    float mean = sum * invM;
    float var  = sumsq * invM - mean * mean;
    float s = rsqrtf(var + BN_EPSC) * g[c];
    float h = be[c] - mean * s;

    int lo = 0, hi = M;
    while (lo < hi) { int m = (lo + hi) >> 1; if (batch[m] < gph) lo = m + 1; else hi = m; }
    int lo2 = lo, hi2 = M;
    while (lo2 < hi2) { int m = (lo2 + hi2) >> 1; if (batch[m] < gph + 1) lo2 = m + 1; else hi2 = m; }
    float mx = -INFINITY;
    for (int rr = lo; rr < lo2; rr++)
        mx = fmaxf(mx, fmaf((float)Hb[(size_t)rr * HIDC + c], s, h));
    sp[c] = mx;
    __syncthreads();
    if (c < NCLSC) {
        float acc = blin[c];
        for (int k = 0; k < HIDC; k++) acc += sp[k] * Wlin[c * HIDC + k];
        out[gph * NCLSC + c] = acc;
    }
}

extern "C" void kernel_launch(void* const* d_in, const int* in_sizes, int n_in,
                              void* d_out, int out_size, void* d_ws, size_t ws_size,
                              hipStream_t stream)
{
    const float* x     = (const float*)d_in[0];
    const int*   ei    = (const int*)d_in[1];
    const int*   batch = (const int*)d_in[2];
    const float* W1l = (const float*)d_in[3];
    const float* b1  = (const float*)d_in[4];
    const float* W1r = (const float*)d_in[5];
    const float* g1  = (const float*)d_in[6];
    const float* be1 = (const float*)d_in[7];
    const float* W2l = (const float*)d_in[8];
    const float* b2  = (const float*)d_in[9];
    const float* W2r = (const float*)d_in[10];
    const float* g2  = (const float*)d_in[11];
    const float* be2 = (const float*)d_in[12];
    const float* W3l = (const float*)d_in[13];
    const float* b3  = (const float*)d_in[14];
    const float* W3r = (const float*)d_in[15];
    const float* g3  = (const float*)d_in[16];
    const float* be3 = (const float*)d_in[17];
    const float* Wlin = (const float*)d_in[18];
    const float* blin = (const float*)d_in[19];

    const int M = N_NODESC;

    // workspace carve (16B aligned)
    char* w = (char*)d_ws;
    bf16_t* Plb  = (bf16_t*)w;  w += (size_t)M * HIDC * 2;
    bf16_t* Prb  = (bf16_t*)w;  w += (size_t)M * HIDC * 2;
    bf16_t* Hb   = (bf16_t*)w;  w += (size_t)M * HIDC * 2;
    bf16_t* Wb1  = (bf16_t*)w;  w += (size_t)256 * IN_DIMC * 2;
    bf16_t* Wb2  = (bf16_t*)w;  w += (size_t)256 * HIDC * 2;
    bf16_t* Wb3  = (bf16_t*)w;  w += (size_t)256 * HIDC * 2;
    int*   rowptr= (int*)w;     w += (size_t)(M + 16) * 4;
    int*   col   = (int*)w;     w += (size_t)N_EDGESC * 4;
    int*   cursor= (int*)w;     w += (size_t)M * 4;
    int*   degi  = (int*)w;     w += (size_t)M * 4;
    int*   slocal= (int*)w;     w += (size_t)M * 4;
    int*   spart = (int*)w;     w += 256 * 4;
    float* stats = (float*)w;   w += (size_t)3 * NREP * 256 * 4;   // zeroed in init

    float* stats1 = stats;
    float* stats2 = stats + NREP * 256;
    float* stats3 = stats + 2 * NREP * 256;

    const int nP = (M + 127) / 128;                     // 391
    const dim3 l1_grid(nP);                             // fused 128x256 tile
    const dim3 hid_grid(((nP + 7) / 8) * 16);           // pair-colocation decode
    const int agg_blocks = (M + NB_AGG - 1) / NB_AGG;
    const int init_total = 2 * 128 * IN_DIMC + 4 * 128 * HIDC + 3 * NREP * 256 + M;

    // ---- init (weights + zeros, one dispatch) ----
    init_kernel<<<(init_total + 255) / 256, 256, 0, stream>>>(W1l, W1r, W2l, W2r, W3l, W3r,
                                                              Wb1, Wb2, Wb3, degi, stats);
    // ---- CSR build (4 dispatches) ----
    degi_kernel<<<(N_EDGESC + 255) / 256, 256, 0, stream>>>(ei, degi);
    scan1_kernel<<<SCAN_NB, 256, 0, stream>>>(degi, slocal, spart);
    scan3_kernel<<<SCAN_NB, 256, 0, stream>>>(slocal, spart, rowptr, cursor);
    fill_kernel<<<(N_EDGESC + 255) / 256, 256, 0, stream>>>(ei, cursor, col);

    // ---- layer 1 (K=768, fused 128x256 tile) ----
    gemm_l1_kernel<<<l1_grid, 256, 0, stream>>>(x, Wb1, Plb, Prb, M);
    agg_combine_kernel<<<agg_blocks, 128, 0, stream>>>(rowptr, col, Plb, Prb, b1, Hb, stats1, M);

    // ---- layer 2 (K=128; BN1 finalize + BN1+ReLU fused into the GEMM) ----
    gemm_hid_kernel<<<hid_grid, 256, 0, stream>>>(Hb, Wb2, stats1, g1, be1, Plb, Prb, M);
    agg_combine_kernel<<<agg_blocks, 128, 0, stream>>>(rowptr, col, Plb, Prb, b2, Hb, stats2, M);

    // ---- layer 3 (K=128; BN2 finalize + BN2+ReLU fused) ----
    gemm_hid_kernel<<<hid_grid, 256, 0, stream>>>(Hb, Wb3, stats2, g2, be2, Plb, Prb, M);
    agg_combine_kernel<<<agg_blocks, 128, 0, stream>>>(rowptr, col, Plb, Prb, b3, Hb, stats3, M);

    // ---- BN3 finalize + pool + head (one dispatch) ----
    poolhead_kernel<<<N_GRAPHSC, 128, 0, stream>>>(Hb, stats3, g3, be3, batch, Wlin, blin,
                                                   (float*)d_out, M);
}